// Round 10
// baseline (366.713 us; speedup 1.0000x reference)
//
#include <hip/hip_runtime.h>

// GAT layer: B=8, N=1024, F_IN=25, H=8, D=16, f32 I/O.
// out0 = relu(h_prime) (8,1024,128) f32 ; out1 = alpha (8,8,1024,1024) f32
//
// Key identity: e[i,j] = ei[i] + ej[j]; softmax over j is invariant to the
// per-row constant ei[i]  =>  alpha[i,j] = mask*exp(ej[j]) / sum_j mask*exp(ej[j]).
// prep_once stores exp(ej) directly, so gat_main has NO transcendentals at all.
//
// Round-10: ZERO-BARRIER wave-independent gat_main (retry of R9 with reduced
// register pressure: no staging arrays, no rv/fb arrays). Each wave owns 16
// rows end-to-end; LDS transpose tile is wave-private (in-wave DS ordering,
// no __syncthreads, no mid-kernel vmcnt(0) barrier drains). Grid 1024 =
// 4 blocks/CU = one residency generation.
#define L2E 1.44269504f

typedef short short8_t  __attribute__((ext_vector_type(8)));
typedef float fltx4     __attribute__((ext_vector_type(4)));
typedef int   intx4     __attribute__((ext_vector_type(4)));
typedef unsigned short ushort4_t __attribute__((ext_vector_type(4)));
typedef unsigned int uint32;

__device__ __forceinline__ unsigned short f2bf(float f) {
    uint32 u = __float_as_uint(f);
    u += 0x7FFFu + ((u >> 16) & 1u);   // RNE
    return (unsigned short)(u >> 16);
}

// ---------------------------------------------------------------------------
// prep_once: per (bh, n): Wh row (f32 -> bf16, MFMA B-frag layout in ws),
// pexp = exp(Wh.a_dst) (f32 in ws). (ei cancels in softmax; exp precomputed.)
//   whb[ bh*16384 + ((n>>5)*64 + ((n>>3)&3)*16 + d)*8 + (n&7) ] = Wh[n][d]
// ---------------------------------------------------------------------------
__global__ __launch_bounds__(256) void prep_once(
    const float* __restrict__ x,      // (8,1024,25)
    const float* __restrict__ W,      // (8,25,16)
    const float* __restrict__ a,      // (8,32)
    float* __restrict__ pexp_ws,      // (64,1024)  exp(ej)
    unsigned short* __restrict__ whb) // (64,32,64,8) bf16
{
    int t  = blockIdx.x * 256 + threadIdx.x;   // 65536
    int bh = t >> 10, n = t & 1023;
    int b  = bh >> 3, h = bh & 7;

    const float* xr = x + ((size_t)(b * 1024 + n)) * 25;
    const float* Wp = W + h * 400;
    const float* ap = a + h * 32;

    float xf[25];
    #pragma unroll
    for (int f = 0; f < 25; ++f) xf[f] = xr[f];

    int base = ((bh * 32 + (n >> 5)) * 64 + ((n >> 3) & 3) * 16) * 8 + (n & 7);
    float vj = 0.f;
    #pragma unroll
    for (int d = 0; d < 16; ++d) {
        float s = 0.f;
        #pragma unroll
        for (int f = 0; f < 25; ++f) s += xf[f] * Wp[f * 16 + d];
        vj += s * ap[16 + d];
        whb[base + d * 8] = f2bf(s);
    }
    pexp_ws[t] = exp2f(vj * L2E);
}

// ---------------------------------------------------------------------------
// gat_main: one block per (b, 64-row chunk, h). 1024 blocks x 256 thr.
// XCD decode: blk%8 = XCD slot, bits 3..5 = h -> 8 head-blocks sharing one
// adj chunk are consecutive on one XCD (adj L2 reuse).
// Wave-independent: wave w owns rows i0 = chunk*64 + w*16 .. +15.
// No __syncthreads anywhere; LDS tile is wave-private.
// ---------------------------------------------------------------------------
__global__ __launch_bounds__(256) void gat_main(
    const int*   __restrict__ adj,    // (8,1024,1024)
    const float* __restrict__ pexp_ws,
    const unsigned short* __restrict__ whb,
    float* __restrict__ out0,         // (8,1024,128)
    float* __restrict__ out1)         // (8,8,1024,1024)
{
    __shared__ __align__(16) unsigned short tlds[4][16][256];  // 32 KB: 8KB/wave

    const int blk   = blockIdx.x;       // 0..1023
    const int x8    = blk & 7;          // XCD slot (round-robin dispatch)
    const int h     = (blk >> 3) & 7;   // h fastest within an XCD -> adj reuse
    const int s     = blk >> 6;         // 0..15
    const int c     = s * 8 + x8;       // 0..127 = (b, chunk)
    const int b     = c >> 4;
    const int chunk = c & 15;           // 64-row chunk
    const int bh    = b * 8 + h;
    const int wave  = threadIdx.x >> 6;
    const int lane  = threadIdx.x & 63;
    const int i0    = chunk * 64 + wave * 16;   // this wave's 16 rows

    // exp(ej) for this lane's 16 columns (precomputed by prep)
    const fltx4* pe4 = (const fltx4*)(pexp_ws + bh * 1024);
    fltx4 expr_[4];
    #pragma unroll
    for (int j0 = 0; j0 < 4; ++j0) expr_[j0] = pe4[j0 * 64 + lane];

    float* abase = out1 + (size_t)bh * 1024 * 1024;

    // ---- adj -> 16-bit masks (round-6 pattern: load consumed immediately) ----
    const intx4* adjb = (const intx4*)(adj + ((size_t)b * 1024 + i0) * 1024);
    uint32 msk[16];
    #pragma unroll
    for (int r = 0; r < 16; ++r) {
        uint32 m = 0;
        #pragma unroll
        for (int j0 = 0; j0 < 4; ++j0) {
            intx4 a4 = adjb[r * 256 + j0 * 64 + lane];
            m |= (a4.x ? (1u << (j0 * 4 + 0)) : 0u);
            m |= (a4.y ? (1u << (j0 * 4 + 1)) : 0u);
            m |= (a4.z ? (1u << (j0 * 4 + 2)) : 0u);
            m |= (a4.w ? (1u << (j0 * 4 + 3)) : 0u);
        }
        msk[r] = m;
    }

    // ---- lane-local sums, then 6 shuffle rounds x 16 interleaved chains ----
    float sum[16];
    #pragma unroll
    for (int r = 0; r < 16; ++r) {
        float s0 = 0.f;
        const uint32 m = msk[r];
        #pragma unroll
        for (int j0 = 0; j0 < 4; ++j0) {
            fltx4 ev = expr_[j0];
            s0 += ((m >> (j0 * 4 + 0)) & 1u) ? ev.x : 0.f;
            s0 += ((m >> (j0 * 4 + 1)) & 1u) ? ev.y : 0.f;
            s0 += ((m >> (j0 * 4 + 2)) & 1u) ? ev.z : 0.f;
            s0 += ((m >> (j0 * 4 + 3)) & 1u) ? ev.w : 0.f;
        }
        sum[r] = s0;
    }
    #pragma unroll
    for (int off = 32; off; off >>= 1) {
        #pragma unroll
        for (int r = 0; r < 16; ++r) sum[r] += __shfl_xor(sum[r], off);
    }

    // ---- per-256-col tile: normalize -> NT store -> LDS transpose -> MFMA ----
    char* tl = (char*)&tlds[wave][0][0];         // wave-private 8 KB tile
    const unsigned short* bbase = whb + (size_t)bh * 16384;
    const int mrow = lane & 15;
    const int quad = lane >> 4;
    fltx4 acc = {0.f, 0.f, 0.f, 0.f};

    #pragma unroll
    for (int j0 = 0; j0 < 4; ++j0) {
        fltx4 ev = expr_[j0];
        #pragma unroll
        for (int r = 0; r < 16; ++r) {
            const bool ok = sum[r] > 0.f;                    // wave-uniform
            const float rinv = ok ? __builtin_amdgcn_rcpf(sum[r]) : 0.f;
            const float fbv  = ok ? 0.f : (1.0f / 1024.0f);  // fully-masked row
            const uint32 m = msk[r] >> (j0 * 4);
            fltx4 st;
            st.x = (m & 1u) ? ev.x * rinv + fbv : fbv;
            st.y = (m & 2u) ? ev.y * rinv + fbv : fbv;
            st.z = (m & 4u) ? ev.z * rinv + fbv : fbv;
            st.w = (m & 8u) ? ev.w * rinv + fbv : fbv;
            // streaming output, never re-read -> nontemporal
            __builtin_nontemporal_store(st,
                (fltx4*)(abase + (size_t)(i0 + r) * 1024 + j0 * 256 + lane * 4));
            // bf16 transpose write, XOR-swizzled within the 512B row
            ushort4_t bv;
            bv.x = f2bf(st.x); bv.y = f2bf(st.y);
            bv.z = f2bf(st.z); bv.w = f2bf(st.w);
            *(ushort4_t*)(tl + r * 512 + ((lane * 8) ^ ((r & 7) << 4))) = bv;
        }
        // wave-local LDS RAW: in-wave DS ordering + lgkmcnt (no barrier)
        #pragma unroll
        for (int kl = 0; kl < 8; ++kl) {
            short8_t afr = *(const short8_t*)(tl + mrow * 512 +
                             ((kl * 64 + quad * 16) ^ ((mrow & 7) << 4)));
            short8_t bfr = *(const short8_t*)(bbase + (((j0 * 8 + kl) * 64 + lane) << 3));
            acc = __builtin_amdgcn_mfma_f32_16x16x32_bf16(afr, bfr, acc, 0, 0, 0);
        }
    }

    // C layout: col = mrow (=d), row = quad*4 + reg; rows are wave-local
    #pragma unroll
    for (int r = 0; r < 4; ++r) {
        const int i = i0 + quad * 4 + r;
        float v = acc[r] > 0.f ? acc[r] : 0.f;
        out0[((size_t)(b * 1024 + i)) * 128 + h * 16 + mrow] = v;
    }
}

// ---------------------------------------------------------------------------
// Fallback: fused kernel (known correct), used if ws_size too small.
// ---------------------------------------------------------------------------
__global__ __launch_bounds__(256) void gat_fused(
    const float* __restrict__ x, const int* __restrict__ adj,
    const float* __restrict__ W, const float* __restrict__ a,
    float* __restrict__ out0, float* __restrict__ out1)
{
    __shared__ __align__(16) unsigned short whb[32 * 64 * 8];
    __shared__ __align__(16) float ej_lds[1024];
    __shared__ float ei_lds[64];
    __shared__ float wa[64];

    const int bh    = blockIdx.x >> 4;
    const int chunk = blockIdx.x & 15;
    const int b     = bh >> 3;
    const int h     = bh & 7;
    const int tid   = threadIdx.x;
    const int wave  = tid >> 6;
    const int lane  = tid & 63;
    const int mrow  = lane & 15;
    const int quad  = lane >> 4;

    const float* Wp = W + h * 400;
    const float* ap = a + h * 32;
    const float* xb = x + (size_t)b * 1024 * 25;

    if (tid < 50) {
        int f = tid % 25, which = tid / 25;
        float s = 0.f;
        #pragma unroll
        for (int d = 0; d < 16; ++d) s += Wp[f * 16 + d] * ap[which * 16 + d];
        wa[which * 32 + f] = s;
    }
    __syncthreads();

    for (int s = 0; s < 4; ++s) {
        int n = tid + (s << 8);
        const float* xr = xb + n * 25;
        float xf[25];
        #pragma unroll
        for (int f = 0; f < 25; ++f) xf[f] = xr[f];
        float vi = 0.f, vj = 0.f;
        #pragma unroll
        for (int f = 0; f < 25; ++f) { vi += xf[f] * wa[f]; vj += xf[f] * wa[32 + f]; }
        ej_lds[n] = vj;
        if ((n >> 6) == chunk) ei_lds[n & 63] = vi;
        int base = (((n >> 5) * 64 + ((n >> 3) & 3) * 16) << 3) + (n & 7);
        #pragma unroll
        for (int d = 0; d < 16; ++d) {
            float s2 = 0.f;
            #pragma unroll
            for (int f = 0; f < 25; ++f) s2 += xf[f] * Wp[f * 16 + d];
            whb[base + d * 8] = f2bf(s2);
        }
    }
    __syncthreads();

    const int i0 = chunk * 64 + wave * 16;
    float* abase = out1 + (size_t)bh * 1024 * 1024;
    const fltx4* ej4 = (const fltx4*)ej_lds;

    for (int r = 0; r < 16; ++r) {
        int i = i0 + r;
        float s_ei = ei_lds[wave * 16 + r];
        const intx4* adj4 = (const intx4*)(adj + ((size_t)b * 1024 + i) * 1024);
        float p[16];
        float sum = 0.f;
        #pragma unroll
        for (int j0 = 0; j0 < 4; ++j0) {
            intx4 av = adj4[j0 * 64 + lane];
            fltx4 ev = ej4[j0 * 64 + lane];
            float p0 = av.x ? exp2f((s_ei + ev.x) * L2E) : 0.f;
            float p1 = av.y ? exp2f((s_ei + ev.y) * L2E) : 0.f;
            float p2 = av.z ? exp2f((s_ei + ev.z) * L2E) : 0.f;
            float p3 = av.w ? exp2f((s_ei + ev.w) * L2E) : 0.f;
            p[j0 * 4 + 0] = p0; p[j0 * 4 + 1] = p1;
            p[j0 * 4 + 2] = p2; p[j0 * 4 + 3] = p3;
            sum += (p0 + p1) + (p2 + p3);
        }
        #pragma unroll
        for (int off = 32; off; off >>= 1) sum += __shfl_xor(sum, off);
        float rinv;
        if (sum > 0.f) {
            rinv = __builtin_amdgcn_rcpf(sum);
        } else {
            rinv = 1.0f;
            #pragma unroll
            for (int k = 0; k < 16; ++k) p[k] = 1.0f / 1024.0f;
        }
        float* arow = abase + (size_t)i * 1024;
        #pragma unroll
        for (int j0 = 0; j0 < 4; ++j0) {
            fltx4 st;
            st.x = p[j0 * 4 + 0] * rinv; st.y = p[j0 * 4 + 1] * rinv;
            st.z = p[j0 * 4 + 2] * rinv; st.w = p[j0 * 4 + 3] * rinv;
            *(fltx4*)(arow + (j0 * 64 + lane) * 4) = st;
        }
    }

    __builtin_amdgcn_fence(__ATOMIC_ACQ_REL, "workgroup");

    const float* aptr = abase + (size_t)(i0 + mrow) * 1024 + quad * 8;
    fltx4 acc = {0.f, 0.f, 0.f, 0.f};
    for (int ks = 0; ks < 32; ++ks) {
        fltx4 a0 = *(const fltx4*)(aptr + ks * 32);
        fltx4 a1 = *(const fltx4*)(aptr + ks * 32 + 4);
        short8_t afr;
        #pragma unroll
        for (int q = 0; q < 4; ++q) {
            afr[q]     = (short)f2bf(a0[q]);
            afr[4 + q] = (short)f2bf(a1[q]);
        }
        short8_t bfr = *(const short8_t*)&whb[((ks * 64 + lane) << 3)];
        acc = __builtin_amdgcn_mfma_f32_16x16x32_bf16(afr, bfr, acc, 0, 0, 0);
    }
    #pragma unroll
    for (int r = 0; r < 4; ++r) {
        int i = i0 + quad * 4 + r;
        float v = acc[r] > 0.f ? acc[r] : 0.f;
        out0[((size_t)(b * 1024 + i)) * 128 + h * 16 + mrow] = v;
    }
}

extern "C" void kernel_launch(void* const* d_in, const int* in_sizes, int n_in,
                              void* d_out, int out_size, void* d_ws, size_t ws_size,
                              hipStream_t stream) {
    const float* x   = (const float*)d_in[0];
    const int*   adj = (const int*)d_in[1];
    const float* W   = (const float*)d_in[2];
    const float* a   = (const float*)d_in[3];

    float* out0 = (float*)d_out;                    // (8,1024,128)
    float* out1 = out0 + (size_t)8 * 1024 * 128;    // (8,8,1024,1024)

    const size_t WHB_BYTES = (size_t)64 * 16384 * 2;      // 2 MB
    const size_t EJ_BYTES  = (size_t)64 * 1024 * 4;       // 256 KB
    const size_t NEED      = WHB_BYTES + EJ_BYTES;        // 2.25 MB

    if (ws_size >= NEED) {
        unsigned short* whb = (unsigned short*)d_ws;
        float* pexp_ws = (float*)((char*)d_ws + WHB_BYTES);
        prep_once<<<256, 256, 0, stream>>>(x, W, a, pexp_ws, whb);
        gat_main<<<1024, 256, 0, stream>>>(adj, pexp_ws, whb, out0, out1);
    } else {
        gat_fused<<<1024, 256, 0, stream>>>(x, adj, W, a, out0, out1);
    }
}

// Round 11
// 302.485 us; speedup vs baseline: 1.2123x; 1.2123x over previous
//
#include <hip/hip_runtime.h>

// GAT layer: B=8, N=1024, F_IN=25, H=8, D=16, f32 I/O.
// out0 = relu(h_prime) (8,1024,128) f32 ; out1 = alpha (8,8,1024,1024) f32
//
// Key identity: e[i,j] = ei[i] + ej[j]; softmax over j is invariant to the
// per-row constant ei[i]  =>  alpha[i,j] = mask*exp(ej[j]) / sum_j mask*exp(ej[j]).
// prep_once stores exp(ej) directly, so gat_main has NO transcendentals at all.
//
// Round-11: H-MERGED blocks. One block per (b, 16-row chunk); adj loaded ONCE
// into 16-bit register masks and reused for ALL 8 heads (h-loop inside the
// block). adj HBM traffic = 33.5 MB by construction, independent of any
// XCD dispatch-mapping assumption (the previous "blk%8=XCD" L2-sharing
// heuristic was never validated and is the prime suspect for the stubborn
// ~130us gat_main: 8x adj refetch = +235 MB of HBM flow).
#define L2E 1.44269504f

typedef short short8_t  __attribute__((ext_vector_type(8)));
typedef float fltx4     __attribute__((ext_vector_type(4)));
typedef int   intx4     __attribute__((ext_vector_type(4)));
typedef unsigned short ushort4_t __attribute__((ext_vector_type(4)));
typedef unsigned int uint32;

__device__ __forceinline__ unsigned short f2bf(float f) {
    uint32 u = __float_as_uint(f);
    u += 0x7FFFu + ((u >> 16) & 1u);   // RNE
    return (unsigned short)(u >> 16);
}

// ---------------------------------------------------------------------------
// prep_once: per (bh, n): Wh row (f32 -> bf16, MFMA B-frag layout in ws),
// pexp = exp(Wh.a_dst) (f32 in ws). (ei cancels in softmax; exp precomputed.)
//   whb[ bh*16384 + ((n>>5)*64 + ((n>>3)&3)*16 + d)*8 + (n&7) ] = Wh[n][d]
// ---------------------------------------------------------------------------
__global__ __launch_bounds__(256) void prep_once(
    const float* __restrict__ x,      // (8,1024,25)
    const float* __restrict__ W,      // (8,25,16)
    const float* __restrict__ a,      // (8,32)
    float* __restrict__ pexp_ws,      // (64,1024)  exp(ej)
    unsigned short* __restrict__ whb) // (64,32,64,8) bf16
{
    int t  = blockIdx.x * 256 + threadIdx.x;   // 65536
    int bh = t >> 10, n = t & 1023;
    int b  = bh >> 3, h = bh & 7;

    const float* xr = x + ((size_t)(b * 1024 + n)) * 25;
    const float* Wp = W + h * 400;
    const float* ap = a + h * 32;

    float xf[25];
    #pragma unroll
    for (int f = 0; f < 25; ++f) xf[f] = xr[f];

    int base = ((bh * 32 + (n >> 5)) * 64 + ((n >> 3) & 3) * 16) * 8 + (n & 7);
    float vj = 0.f;
    #pragma unroll
    for (int d = 0; d < 16; ++d) {
        float s = 0.f;
        #pragma unroll
        for (int f = 0; f < 25; ++f) s += xf[f] * Wp[f * 16 + d];
        vj += s * ap[16 + d];
        whb[base + d * 8] = f2bf(s);
    }
    pexp_ws[t] = exp2f(vj * L2E);
}

// ---------------------------------------------------------------------------
// gat_main: one block per (b, 16-row chunk). 512 blocks x 256 thr (4 waves).
// Wave w owns rows i0 = chunk*16 + w*4 .. +3, END-TO-END for all 8 heads:
//   adj -> msk[4] (read once), then per h: {exp(ej) regs, masked sums,
//   shuffle-reduce, normalize, NT alpha store, bf16 -> wave-private LDS tile,
//   32 MFMAs (A-tile rows 0-3 valid; duplicated rows discarded)}.
// No __syncthreads (wave-private LDS, in-wave DS ordering).
// ---------------------------------------------------------------------------
__global__ __launch_bounds__(256) void gat_main(
    const int*   __restrict__ adj,    // (8,1024,1024)
    const float* __restrict__ pexp_ws,
    const unsigned short* __restrict__ whb,
    float* __restrict__ out0,         // (8,1024,128)
    float* __restrict__ out1)         // (8,8,1024,1024)
{
    __shared__ __align__(16) unsigned short tlds[4][4][1024];  // 32 KB: 8KB/wave

    const int blk   = blockIdx.x;        // 0..511
    const int b     = blk >> 6;
    const int chunk = blk & 63;          // 16-row chunk
    const int wave  = threadIdx.x >> 6;
    const int lane  = threadIdx.x & 63;
    const int i0    = chunk * 16 + wave * 4;   // this wave's 4 rows
    const int mrow  = lane & 15;
    const int quad  = lane >> 4;

    // ---- adj -> 16-bit masks, read ONCE, reused for all 8 heads ----
    const intx4* adjb = (const intx4*)(adj + ((size_t)b * 1024 + i0) * 1024);
    uint32 msk[4];
    #pragma unroll
    for (int r = 0; r < 4; ++r) {
        uint32 m = 0;
        #pragma unroll
        for (int j0 = 0; j0 < 4; ++j0) {
            intx4 a4 = adjb[r * 256 + j0 * 64 + lane];
            m |= (a4.x ? (1u << (j0 * 4 + 0)) : 0u);
            m |= (a4.y ? (1u << (j0 * 4 + 1)) : 0u);
            m |= (a4.z ? (1u << (j0 * 4 + 2)) : 0u);
            m |= (a4.w ? (1u << (j0 * 4 + 3)) : 0u);
        }
        msk[r] = m;
    }

    char* tl = (char*)&tlds[wave][0][0];   // wave-private 8 KB tile (4 rows)

    for (int h = 0; h < 8; ++h) {
        const int bh = b * 8 + h;

        // exp(ej) for this lane's 16 columns of head h
        const fltx4* pe4 = (const fltx4*)(pexp_ws + bh * 1024);
        fltx4 ev[4];
        #pragma unroll
        for (int j0 = 0; j0 < 4; ++j0) ev[j0] = pe4[j0 * 64 + lane];

        // masked lane-local sums, 4 rows
        float sum[4];
        #pragma unroll
        for (int r = 0; r < 4; ++r) {
            float s0 = 0.f;
            const uint32 m = msk[r];
            #pragma unroll
            for (int j0 = 0; j0 < 4; ++j0) {
                s0 += ((m >> (j0 * 4 + 0)) & 1u) ? ev[j0].x : 0.f;
                s0 += ((m >> (j0 * 4 + 1)) & 1u) ? ev[j0].y : 0.f;
                s0 += ((m >> (j0 * 4 + 2)) & 1u) ? ev[j0].z : 0.f;
                s0 += ((m >> (j0 * 4 + 3)) & 1u) ? ev[j0].w : 0.f;
            }
            sum[r] = s0;
        }
        #pragma unroll
        for (int off = 32; off; off >>= 1) {
            #pragma unroll
            for (int r = 0; r < 4; ++r) sum[r] += __shfl_xor(sum[r], off);
        }

        // normalize + NT alpha store + bf16 LDS transpose write
        float* abase = out1 + (size_t)bh * 1024 * 1024;
        #pragma unroll
        for (int r = 0; r < 4; ++r) {
            const bool ok = sum[r] > 0.f;                    // wave-uniform
            const float rinv = ok ? __builtin_amdgcn_rcpf(sum[r]) : 0.f;
            const float fbv  = ok ? 0.f : (1.0f / 1024.0f);  // fully-masked row
            const uint32 m = msk[r];
            const int swz = r << 6;                          // bank-spread key
            #pragma unroll
            for (int j0 = 0; j0 < 4; ++j0) {
                fltx4 st;
                st.x = ((m >> (j0 * 4 + 0)) & 1u) ? ev[j0].x * rinv + fbv : fbv;
                st.y = ((m >> (j0 * 4 + 1)) & 1u) ? ev[j0].y * rinv + fbv : fbv;
                st.z = ((m >> (j0 * 4 + 2)) & 1u) ? ev[j0].z * rinv + fbv : fbv;
                st.w = ((m >> (j0 * 4 + 3)) & 1u) ? ev[j0].w * rinv + fbv : fbv;
                // streaming output, never re-read -> nontemporal
                __builtin_nontemporal_store(st,
                    (fltx4*)(abase + (size_t)(i0 + r) * 1024 + j0 * 256 + lane * 4));
                ushort4_t bv;
                bv.x = f2bf(st.x); bv.y = f2bf(st.y);
                bv.z = f2bf(st.z); bv.w = f2bf(st.w);
                *(ushort4_t*)(tl + r * 2048 + ((j0 * 512 + lane * 8) ^ swz)) = bv;
            }
        }

        // Phase B: h_prime rows i0..i0+3 = alpha(4x1024) @ Wh(1024x16).
        // A-tile rows 0-3 valid; lanes mrow>=4 read duplicated rows (discarded).
        const unsigned short* bbase = whb + (size_t)bh * 16384;
        const int arow = mrow & 3;
        const int aswz = arow << 6;
        fltx4 acc = {0.f, 0.f, 0.f, 0.f};
        #pragma unroll 8
        for (int ks = 0; ks < 32; ++ks) {
            short8_t afr = *(const short8_t*)(tl + arow * 2048 +
                             ((ks * 64 + quad * 16) ^ aswz));
            short8_t bfr = *(const short8_t*)(bbase + ((ks * 64 + lane) << 3));
            acc = __builtin_amdgcn_mfma_f32_16x16x32_bf16(afr, bfr, acc, 0, 0, 0);
        }
        // C layout: col = mrow (=d), row = quad*4 + reg -> rows 0-3 live in quad 0
        if (quad == 0) {
            #pragma unroll
            for (int r = 0; r < 4; ++r) {
                float v = acc[r] > 0.f ? acc[r] : 0.f;
                out0[((size_t)(b * 1024 + i0 + r)) * 128 + h * 16 + mrow] = v;
            }
        }
    }
}

// ---------------------------------------------------------------------------
// Fallback: fused kernel (known correct), used if ws_size too small.
// ---------------------------------------------------------------------------
__global__ __launch_bounds__(256) void gat_fused(
    const float* __restrict__ x, const int* __restrict__ adj,
    const float* __restrict__ W, const float* __restrict__ a,
    float* __restrict__ out0, float* __restrict__ out1)
{
    __shared__ __align__(16) unsigned short whb[32 * 64 * 8];
    __shared__ __align__(16) float ej_lds[1024];
    __shared__ float ei_lds[64];
    __shared__ float wa[64];

    const int bh    = blockIdx.x >> 4;
    const int chunk = blockIdx.x & 15;
    const int b     = bh >> 3;
    const int h     = bh & 7;
    const int tid   = threadIdx.x;
    const int wave  = tid >> 6;
    const int lane  = tid & 63;
    const int mrow  = lane & 15;
    const int quad  = lane >> 4;

    const float* Wp = W + h * 400;
    const float* ap = a + h * 32;
    const float* xb = x + (size_t)b * 1024 * 25;

    if (tid < 50) {
        int f = tid % 25, which = tid / 25;
        float s = 0.f;
        #pragma unroll
        for (int d = 0; d < 16; ++d) s += Wp[f * 16 + d] * ap[which * 16 + d];
        wa[which * 32 + f] = s;
    }
    __syncthreads();

    for (int s = 0; s < 4; ++s) {
        int n = tid + (s << 8);
        const float* xr = xb + n * 25;
        float xf[25];
        #pragma unroll
        for (int f = 0; f < 25; ++f) xf[f] = xr[f];
        float vi = 0.f, vj = 0.f;
        #pragma unroll
        for (int f = 0; f < 25; ++f) { vi += xf[f] * wa[f]; vj += xf[f] * wa[32 + f]; }
        ej_lds[n] = vj;
        if ((n >> 6) == chunk) ei_lds[n & 63] = vi;
        int base = (((n >> 5) * 64 + ((n >> 3) & 3) * 16) << 3) + (n & 7);
        #pragma unroll
        for (int d = 0; d < 16; ++d) {
            float s2 = 0.f;
            #pragma unroll
            for (int f = 0; f < 25; ++f) s2 += xf[f] * Wp[f * 16 + d];
            whb[base + d * 8] = f2bf(s2);
        }
    }
    __syncthreads();

    const int i0 = chunk * 64 + wave * 16;
    float* abase = out1 + (size_t)bh * 1024 * 1024;
    const fltx4* ej4 = (const fltx4*)ej_lds;

    for (int r = 0; r < 16; ++r) {
        int i = i0 + r;
        float s_ei = ei_lds[wave * 16 + r];
        const intx4* adj4 = (const intx4*)(adj + ((size_t)b * 1024 + i) * 1024);
        float p[16];
        float sum = 0.f;
        #pragma unroll
        for (int j0 = 0; j0 < 4; ++j0) {
            intx4 av = adj4[j0 * 64 + lane];
            fltx4 ev = ej4[j0 * 64 + lane];
            float p0 = av.x ? exp2f((s_ei + ev.x) * L2E) : 0.f;
            float p1 = av.y ? exp2f((s_ei + ev.y) * L2E) : 0.f;
            float p2 = av.z ? exp2f((s_ei + ev.z) * L2E) : 0.f;
            float p3 = av.w ? exp2f((s_ei + ev.w) * L2E) : 0.f;
            p[j0 * 4 + 0] = p0; p[j0 * 4 + 1] = p1;
            p[j0 * 4 + 2] = p2; p[j0 * 4 + 3] = p3;
            sum += (p0 + p1) + (p2 + p3);
        }
        #pragma unroll
        for (int off = 32; off; off >>= 1) sum += __shfl_xor(sum, off);
        float rinv;
        if (sum > 0.f) {
            rinv = __builtin_amdgcn_rcpf(sum);
        } else {
            rinv = 1.0f;
            #pragma unroll
            for (int k = 0; k < 16; ++k) p[k] = 1.0f / 1024.0f;
        }
        float* arow = abase + (size_t)i * 1024;
        #pragma unroll
        for (int j0 = 0; j0 < 4; ++j0) {
            fltx4 st;
            st.x = p[j0 * 4 + 0] * rinv; st.y = p[j0 * 4 + 1] * rinv;
            st.z = p[j0 * 4 + 2] * rinv; st.w = p[j0 * 4 + 3] * rinv;
            *(fltx4*)(arow + (j0 * 64 + lane) * 4) = st;
        }
    }

    __builtin_amdgcn_fence(__ATOMIC_ACQ_REL, "workgroup");

    const float* aptr = abase + (size_t)(i0 + mrow) * 1024 + quad * 8;
    fltx4 acc = {0.f, 0.f, 0.f, 0.f};
    for (int ks = 0; ks < 32; ++ks) {
        fltx4 a0 = *(const fltx4*)(aptr + ks * 32);
        fltx4 a1 = *(const fltx4*)(aptr + ks * 32 + 4);
        short8_t afr;
        #pragma unroll
        for (int q = 0; q < 4; ++q) {
            afr[q]     = (short)f2bf(a0[q]);
            afr[4 + q] = (short)f2bf(a1[q]);
        }
        short8_t bfr = *(const short8_t*)&whb[((ks * 64 + lane) << 3)];
        acc = __builtin_amdgcn_mfma_f32_16x16x32_bf16(afr, bfr, acc, 0, 0, 0);
    }
    #pragma unroll
    for (int r = 0; r < 4; ++r) {
        int i = i0 + quad * 4 + r;
        float v = acc[r] > 0.f ? acc[r] : 0.f;
        out0[((size_t)(b * 1024 + i)) * 128 + h * 16 + mrow] = v;
    }
}

extern "C" void kernel_launch(void* const* d_in, const int* in_sizes, int n_in,
                              void* d_out, int out_size, void* d_ws, size_t ws_size,
                              hipStream_t stream) {
    const float* x   = (const float*)d_in[0];
    const int*   adj = (const int*)d_in[1];
    const float* W   = (const float*)d_in[2];
    const float* a   = (const float*)d_in[3];

    float* out0 = (float*)d_out;                    // (8,1024,128)
    float* out1 = out0 + (size_t)8 * 1024 * 128;    // (8,8,1024,1024)

    const size_t WHB_BYTES = (size_t)64 * 16384 * 2;      // 2 MB
    const size_t EJ_BYTES  = (size_t)64 * 1024 * 4;       // 256 KB
    const size_t NEED      = WHB_BYTES + EJ_BYTES;        // 2.25 MB

    if (ws_size >= NEED) {
        unsigned short* whb = (unsigned short*)d_ws;
        float* pexp_ws = (float*)((char*)d_ws + WHB_BYTES);
        prep_once<<<256, 256, 0, stream>>>(x, W, a, pexp_ws, whb);
        gat_main<<<512, 256, 0, stream>>>(adj, pexp_ws, whb, out0, out1);
    } else {
        gat_fused<<<1024, 256, 0, stream>>>(x, adj, W, a, out0, out1);
    }
}

// Round 12
// 297.991 us; speedup vs baseline: 1.2306x; 1.0151x over previous
//
#include <hip/hip_runtime.h>

// GAT layer: B=8, N=1024, F_IN=25, H=8, D=16, f32 I/O.
// out0 = relu(h_prime) (8,1024,128) f32 ; out1 = alpha (8,8,1024,1024) f32
//
// Key identity: e[i,j] = ei[i] + ej[j]; softmax over j is invariant to the
// per-row constant ei[i]  =>  alpha[i,j] = mask*exp(ej[j]) / sum_j mask*exp(ej[j]).
// prep_once stores exp(ej) directly, so gat_main has NO transcendentals at all.
//
// Round-12 (on top of R11's h-merge win):
//  * Phase B: block-shared 16-row bf16 alpha tile + K-split across 4 waves
//    (wave w: ks in [8w,8w+8)) + LDS partial reduce. Removes R11's 4x
//    redundant MFMA/tl-read/whb-load (A-rows were duplicated 4x per wave).
//  * pexp(h+1) software-prefetched into registers during head h's stores.
//  * Shared A-tile uses the (row&7)<<4 XOR swizzle (16 distinct rows now
//    read per ds_read_b128 -> needs real conflict-breaking, not duplication).
#define L2E 1.44269504f

typedef short short8_t  __attribute__((ext_vector_type(8)));
typedef float fltx4     __attribute__((ext_vector_type(4)));
typedef int   intx4     __attribute__((ext_vector_type(4)));
typedef unsigned short ushort4_t __attribute__((ext_vector_type(4)));
typedef unsigned int uint32;

__device__ __forceinline__ unsigned short f2bf(float f) {
    uint32 u = __float_as_uint(f);
    u += 0x7FFFu + ((u >> 16) & 1u);   // RNE
    return (unsigned short)(u >> 16);
}

// ---------------------------------------------------------------------------
// prep_once: per (bh, n): Wh row (f32 -> bf16, MFMA B-frag layout in ws),
// pexp = exp(Wh.a_dst) (f32 in ws). (ei cancels in softmax; exp precomputed.)
//   whb[ bh*16384 + ((n>>5)*64 + ((n>>3)&3)*16 + d)*8 + (n&7) ] = Wh[n][d]
// ---------------------------------------------------------------------------
__global__ __launch_bounds__(256) void prep_once(
    const float* __restrict__ x,      // (8,1024,25)
    const float* __restrict__ W,      // (8,25,16)
    const float* __restrict__ a,      // (8,32)
    float* __restrict__ pexp_ws,      // (64,1024)  exp(ej)
    unsigned short* __restrict__ whb) // (64,32,64,8) bf16
{
    int t  = blockIdx.x * 256 + threadIdx.x;   // 65536
    int bh = t >> 10, n = t & 1023;
    int b  = bh >> 3, h = bh & 7;

    const float* xr = x + ((size_t)(b * 1024 + n)) * 25;
    const float* Wp = W + h * 400;
    const float* ap = a + h * 32;

    float xf[25];
    #pragma unroll
    for (int f = 0; f < 25; ++f) xf[f] = xr[f];

    int base = ((bh * 32 + (n >> 5)) * 64 + ((n >> 3) & 3) * 16) * 8 + (n & 7);
    float vj = 0.f;
    #pragma unroll
    for (int d = 0; d < 16; ++d) {
        float s = 0.f;
        #pragma unroll
        for (int f = 0; f < 25; ++f) s += xf[f] * Wp[f * 16 + d];
        vj += s * ap[16 + d];
        whb[base + d * 8] = f2bf(s);
    }
    pexp_ws[t] = exp2f(vj * L2E);
}

// ---------------------------------------------------------------------------
// gat_main: one block per (b, 16-row chunk). 512 blocks x 256 thr (4 waves).
// adj read ONCE into register masks (wave w: rows 4w..4w+3), reused for all
// 8 heads. Per head: {ev regs (prefetched), masked sums, shuffle-reduce,
// normalize -> NT alpha store + bf16 -> SHARED swizzled A-tile; sync;
// K-split MFMA (wave w: ks 8w..8w+7, all 16 A-rows valid); sync;
// wave 0 reduces partials + relu + out0 store}.
// ---------------------------------------------------------------------------
__global__ __launch_bounds__(256) void gat_main(
    const int*   __restrict__ adj,    // (8,1024,1024)
    const float* __restrict__ pexp_ws,
    const unsigned short* __restrict__ whb,
    float* __restrict__ out0,         // (8,1024,128)
    float* __restrict__ out1)         // (8,8,1024,1024)
{
    __shared__ __align__(16) unsigned short atile[16][1024];   // 32 KB bf16 alpha
    __shared__ __align__(16) float accred[4][16][16];          // 4 KB partials

    const int blk   = blockIdx.x;        // 0..511
    const int b     = blk >> 6;
    const int chunk = blk & 63;          // 16-row chunk
    const int wave  = threadIdx.x >> 6;
    const int lane  = threadIdx.x & 63;
    const int i0c   = chunk * 16;        // block's 16 rows
    const int i0w   = i0c + wave * 4;    // this wave's 4 rows (Phase A)
    const int mrow  = lane & 15;
    const int quad  = lane >> 4;

    // ---- adj -> 16-bit masks, read ONCE, reused for all 8 heads ----
    const intx4* adjb = (const intx4*)(adj + ((size_t)b * 1024 + i0w) * 1024);
    uint32 msk[4];
    #pragma unroll
    for (int r = 0; r < 4; ++r) {
        uint32 m = 0;
        #pragma unroll
        for (int j0 = 0; j0 < 4; ++j0) {
            intx4 a4 = adjb[r * 256 + j0 * 64 + lane];
            m |= (a4.x ? (1u << (j0 * 4 + 0)) : 0u);
            m |= (a4.y ? (1u << (j0 * 4 + 1)) : 0u);
            m |= (a4.z ? (1u << (j0 * 4 + 2)) : 0u);
            m |= (a4.w ? (1u << (j0 * 4 + 3)) : 0u);
        }
        msk[r] = m;
    }

    char* tlb = (char*)&atile[0][0];

    // ev for head 0; evn prefetched each iteration
    const fltx4* pe4 = (const fltx4*)(pexp_ws + (size_t)(b * 8) * 1024);
    fltx4 ev[4];
    #pragma unroll
    for (int j0 = 0; j0 < 4; ++j0) ev[j0] = pe4[j0 * 64 + lane];

    for (int h = 0; h < 8; ++h) {
        const int bh = b * 8 + h;

        // masked lane-local sums, 4 rows
        float sum[4];
        #pragma unroll
        for (int r = 0; r < 4; ++r) {
            float s0 = 0.f;
            const uint32 m = msk[r];
            #pragma unroll
            for (int j0 = 0; j0 < 4; ++j0) {
                s0 += ((m >> (j0 * 4 + 0)) & 1u) ? ev[j0].x : 0.f;
                s0 += ((m >> (j0 * 4 + 1)) & 1u) ? ev[j0].y : 0.f;
                s0 += ((m >> (j0 * 4 + 2)) & 1u) ? ev[j0].z : 0.f;
                s0 += ((m >> (j0 * 4 + 3)) & 1u) ? ev[j0].w : 0.f;
            }
            sum[r] = s0;
        }
        #pragma unroll
        for (int off = 32; off; off >>= 1) {
            #pragma unroll
            for (int r = 0; r < 4; ++r) sum[r] += __shfl_xor(sum[r], off);
        }

        // prefetch next head's exp(ej) while stores/MFMA cover the latency
        fltx4 evn[4];
        if (h < 7) {
            const fltx4* pn = (const fltx4*)(pexp_ws + (size_t)(bh + 1) * 1024);
            #pragma unroll
            for (int j0 = 0; j0 < 4; ++j0) evn[j0] = pn[j0 * 64 + lane];
        }

        // normalize + NT alpha store + bf16 -> shared swizzled A-tile
        float* abase = out1 + (size_t)bh * 1024 * 1024;
        #pragma unroll
        for (int r = 0; r < 4; ++r) {
            const bool ok = sum[r] > 0.f;                    // wave-uniform
            const float rinv = ok ? __builtin_amdgcn_rcpf(sum[r]) : 0.f;
            const float fbv  = ok ? 0.f : (1.0f / 1024.0f);  // fully-masked row
            const uint32 m = msk[r];
            const int row  = wave * 4 + r;                   // block-local 0..15
            const int swz  = (row & 7) << 4;
            char* lrow = tlb + row * 2048;
            #pragma unroll
            for (int j0 = 0; j0 < 4; ++j0) {
                fltx4 st;
                st.x = ((m >> (j0 * 4 + 0)) & 1u) ? ev[j0].x * rinv + fbv : fbv;
                st.y = ((m >> (j0 * 4 + 1)) & 1u) ? ev[j0].y * rinv + fbv : fbv;
                st.z = ((m >> (j0 * 4 + 2)) & 1u) ? ev[j0].z * rinv + fbv : fbv;
                st.w = ((m >> (j0 * 4 + 3)) & 1u) ? ev[j0].w * rinv + fbv : fbv;
                // streaming output, never re-read -> nontemporal
                __builtin_nontemporal_store(st,
                    (fltx4*)(abase + (size_t)(i0w + r) * 1024 + j0 * 256 + lane * 4));
                ushort4_t bv;
                bv.x = f2bf(st.x); bv.y = f2bf(st.y);
                bv.z = f2bf(st.z); bv.w = f2bf(st.w);
                *(ushort4_t*)(lrow + ((j0 * 512 + lane * 8) ^ swz)) = bv;
            }
        }

        __syncthreads();   // A-tile complete

        // Phase B (K-split): wave w covers ks = 8w..8w+7; all 16 A-rows valid
        {
            const unsigned short* bbase = whb + (size_t)bh * 16384;
            const int aswz = (mrow & 7) << 4;
            char* lrow = tlb + mrow * 2048;
            fltx4 acc = {0.f, 0.f, 0.f, 0.f};
            #pragma unroll
            for (int kk = 0; kk < 8; ++kk) {
                const int ks = wave * 8 + kk;
                short8_t afr = *(const short8_t*)(lrow + ((ks * 64 + quad * 16) ^ aswz));
                short8_t bfr = *(const short8_t*)(bbase + ((ks * 64 + lane) << 3));
                acc = __builtin_amdgcn_mfma_f32_16x16x32_bf16(afr, bfr, acc, 0, 0, 0);
            }
            // C layout: col = mrow (=d), row = quad*4 + reg
            #pragma unroll
            for (int r = 0; r < 4; ++r)
                accred[wave][quad * 4 + r][mrow] = acc[r];
        }

        __syncthreads();   // partials complete; A-tile reads done

        if (wave == 0) {
            #pragma unroll
            for (int r = 0; r < 4; ++r) {
                const int row = quad * 4 + r;
                float v = (accred[0][row][mrow] + accred[1][row][mrow])
                        + (accred[2][row][mrow] + accred[3][row][mrow]);
                v = v > 0.f ? v : 0.f;
                out0[((size_t)(b * 1024 + i0c + row)) * 128 + h * 16 + mrow] = v;
            }
        }

        #pragma unroll
        for (int j0 = 0; j0 < 4; ++j0) ev[j0] = evn[j0];
    }
}

// ---------------------------------------------------------------------------
// Fallback: fused kernel (known correct), used if ws_size too small.
// ---------------------------------------------------------------------------
__global__ __launch_bounds__(256) void gat_fused(
    const float* __restrict__ x, const int* __restrict__ adj,
    const float* __restrict__ W, const float* __restrict__ a,
    float* __restrict__ out0, float* __restrict__ out1)
{
    __shared__ __align__(16) unsigned short whb[32 * 64 * 8];
    __shared__ __align__(16) float ej_lds[1024];
    __shared__ float ei_lds[64];
    __shared__ float wa[64];

    const int bh    = blockIdx.x >> 4;
    const int chunk = blockIdx.x & 15;
    const int b     = bh >> 3;
    const int h     = bh & 7;
    const int tid   = threadIdx.x;
    const int wave  = tid >> 6;
    const int lane  = tid & 63;
    const int mrow  = lane & 15;
    const int quad  = lane >> 4;

    const float* Wp = W + h * 400;
    const float* ap = a + h * 32;
    const float* xb = x + (size_t)b * 1024 * 25;

    if (tid < 50) {
        int f = tid % 25, which = tid / 25;
        float s = 0.f;
        #pragma unroll
        for (int d = 0; d < 16; ++d) s += Wp[f * 16 + d] * ap[which * 16 + d];
        wa[which * 32 + f] = s;
    }
    __syncthreads();

    for (int s = 0; s < 4; ++s) {
        int n = tid + (s << 8);
        const float* xr = xb + n * 25;
        float xf[25];
        #pragma unroll
        for (int f = 0; f < 25; ++f) xf[f] = xr[f];
        float vi = 0.f, vj = 0.f;
        #pragma unroll
        for (int f = 0; f < 25; ++f) { vi += xf[f] * wa[f]; vj += xf[f] * wa[32 + f]; }
        ej_lds[n] = vj;
        if ((n >> 6) == chunk) ei_lds[n & 63] = vi;
        int base = (((n >> 5) * 64 + ((n >> 3) & 3) * 16) << 3) + (n & 7);
        #pragma unroll
        for (int d = 0; d < 16; ++d) {
            float s2 = 0.f;
            #pragma unroll
            for (int f = 0; f < 25; ++f) s2 += xf[f] * Wp[f * 16 + d];
            whb[base + d * 8] = f2bf(s2);
        }
    }
    __syncthreads();

    const int i0 = chunk * 64 + wave * 16;
    float* abase = out1 + (size_t)bh * 1024 * 1024;
    const fltx4* ej4 = (const fltx4*)ej_lds;

    for (int r = 0; r < 16; ++r) {
        int i = i0 + r;
        float s_ei = ei_lds[wave * 16 + r];
        const intx4* adj4 = (const intx4*)(adj + ((size_t)b * 1024 + i) * 1024);
        float p[16];
        float sum = 0.f;
        #pragma unroll
        for (int j0 = 0; j0 < 4; ++j0) {
            intx4 av = adj4[j0 * 64 + lane];
            fltx4 ev = ej4[j0 * 64 + lane];
            float p0 = av.x ? exp2f((s_ei + ev.x) * L2E) : 0.f;
            float p1 = av.y ? exp2f((s_ei + ev.y) * L2E) : 0.f;
            float p2 = av.z ? exp2f((s_ei + ev.z) * L2E) : 0.f;
            float p3 = av.w ? exp2f((s_ei + ev.w) * L2E) : 0.f;
            p[j0 * 4 + 0] = p0; p[j0 * 4 + 1] = p1;
            p[j0 * 4 + 2] = p2; p[j0 * 4 + 3] = p3;
            sum += (p0 + p1) + (p2 + p3);
        }
        #pragma unroll
        for (int off = 32; off; off >>= 1) sum += __shfl_xor(sum, off);
        float rinv;
        if (sum > 0.f) {
            rinv = __builtin_amdgcn_rcpf(sum);
        } else {
            rinv = 1.0f;
            #pragma unroll
            for (int k = 0; k < 16; ++k) p[k] = 1.0f / 1024.0f;
        }
        float* arow = abase + (size_t)i * 1024;
        #pragma unroll
        for (int j0 = 0; j0 < 4; ++j0) {
            fltx4 st;
            st.x = p[j0 * 4 + 0] * rinv; st.y = p[j0 * 4 + 1] * rinv;
            st.z = p[j0 * 4 + 2] * rinv; st.w = p[j0 * 4 + 3] * rinv;
            *(fltx4*)(arow + (j0 * 64 + lane) * 4) = st;
        }
    }

    __builtin_amdgcn_fence(__ATOMIC_ACQ_REL, "workgroup");

    const float* aptr = abase + (size_t)(i0 + mrow) * 1024 + quad * 8;
    fltx4 acc = {0.f, 0.f, 0.f, 0.f};
    for (int ks = 0; ks < 32; ++ks) {
        fltx4 a0 = *(const fltx4*)(aptr + ks * 32);
        fltx4 a1 = *(const fltx4*)(aptr + ks * 32 + 4);
        short8_t afr;
        #pragma unroll
        for (int q = 0; q < 4; ++q) {
            afr[q]     = (short)f2bf(a0[q]);
            afr[4 + q] = (short)f2bf(a1[q]);
        }
        short8_t bfr = *(const short8_t*)&whb[((ks * 64 + lane) << 3)];
        acc = __builtin_amdgcn_mfma_f32_16x16x32_bf16(afr, bfr, acc, 0, 0, 0);
    }
    #pragma unroll
    for (int r = 0; r < 4; ++r) {
        int i = i0 + quad * 4 + r;
        float v = acc[r] > 0.f ? acc[r] : 0.f;
        out0[((size_t)(b * 1024 + i)) * 128 + h * 16 + mrow] = v;
    }
}

extern "C" void kernel_launch(void* const* d_in, const int* in_sizes, int n_in,
                              void* d_out, int out_size, void* d_ws, size_t ws_size,
                              hipStream_t stream) {
    const float* x   = (const float*)d_in[0];
    const int*   adj = (const int*)d_in[1];
    const float* W   = (const float*)d_in[2];
    const float* a   = (const float*)d_in[3];

    float* out0 = (float*)d_out;                    // (8,1024,128)
    float* out1 = out0 + (size_t)8 * 1024 * 128;    // (8,8,1024,1024)

    const size_t WHB_BYTES = (size_t)64 * 16384 * 2;      // 2 MB
    const size_t EJ_BYTES  = (size_t)64 * 1024 * 4;       // 256 KB
    const size_t NEED      = WHB_BYTES + EJ_BYTES;        // 2.25 MB

    if (ws_size >= NEED) {
        unsigned short* whb = (unsigned short*)d_ws;
        float* pexp_ws = (float*)((char*)d_ws + WHB_BYTES);
        prep_once<<<256, 256, 0, stream>>>(x, W, a, pexp_ws, whb);
        gat_main<<<512, 256, 0, stream>>>(adj, pexp_ws, whb, out0, out1);
    } else {
        gat_fused<<<1024, 256, 0, stream>>>(x, adj, W, a, out0, out1);
    }
}